// Round 1
// baseline (2121.508 us; speedup 1.0000x reference)
//
#include <hip/hip_runtime.h>

#define H 1024
#define I_DIM 128
#define O_DIM 128
#define T_DIM 512
#define ALPHA 0.2f
#define NWG 64          // 4 batch-groups x 16 j-slices
#define GSZ 16          // WGs per batch-group
#define SLICE_U64 96    // 96 self-validating 8B chunks per (WG,wave) slice (32 octets x 3)
#define GRP_U64   (64 * SLICE_U64)   // 6144 u64 = 48 KB per (parity, group)

typedef short short8 __attribute__((ext_vector_type(8)));
typedef float f32x4 __attribute__((ext_vector_type(4)));
typedef unsigned long long ull_alias __attribute__((may_alias));

__device__ __forceinline__ unsigned short f2b(float f) {
    union { float f; unsigned u; } x; x.f = f;
    unsigned u = x.u;
    return (unsigned short)((u + 0x7FFFu + ((u >> 16) & 1u)) >> 16);
}
__device__ __forceinline__ float tanh_fast(float x) {
    float e = __expf(2.0f * x);
    return 1.0f - 2.0f * __builtin_amdgcn_rcpf(e + 1.0f);
}
// 8 contiguous f32 -> bf16 fragment (RNE)
__device__ __forceinline__ short8 ld8f(const float* __restrict__ p) {
    const float4 a = *(const float4*)p;
    const float4 b = *(const float4*)(p + 4);
    short8 r;
    r[0]=(short)f2b(a.x); r[1]=(short)f2b(a.y); r[2]=(short)f2b(a.z); r[3]=(short)f2b(a.w);
    r[4]=(short)f2b(b.x); r[5]=(short)f2b(b.y); r[6]=(short)f2b(b.z); r[7]=(short)f2b(b.w);
    return r;
}

// Packed-A layout per batch-group: A[m][k] at u16 offset
//   (k>>5)*512 + ((k&31)>>3)*128 + m*8 + (k&7)
// Cross-WG exchange: each (WG ji, wave pw) slice = 16 k x 16 m bf16 = 32 octets
// (octet = 8 consecutive u16 of one (m, k-octet)). Each octet is published as
// THREE 8-byte chunks, each chunk = 3 bf16 data (48b) + 16b step tag, stored with
// native relaxed agent-scope 64-bit atomics (single-copy atomic).
//   -> publish is fire-and-forget: no vmcnt(0), no separate tag store.
//   -> consume polls the data itself; the successful poll IS the fetch.
// Stale-tag hazard across launches handled by 0xFF memset of the arena per launch.
__global__ __launch_bounds__(256, 1) void rnn_kernel(
    const float* __restrict__ x, const float* __restrict__ wi,
    const float* __restrict__ wrec, const float* __restrict__ wout,
    const float* __restrict__ bb, const float* __restrict__ gg,
    const float* __restrict__ h0p, float* __restrict__ out,
    unsigned long long* __restrict__ aG)
{
    __shared__ unsigned short abuf[32 * 512];   // 32 KB: group's full a_{t-1}
    __shared__ unsigned short aloc[1024];       // 2 KB: own a_t slice, packed
    __shared__ float opart[4 * 128];            // 2 KB: out k-partials

    const int tid  = threadIdx.x;
    const int w    = tid >> 6, lane = tid & 63;
    const int n    = lane & 15, q = lane >> 4;
    const int grp  = blockIdx.x & 3;
    const int ji   = blockIdx.x >> 2;
    const int j0   = ji * 64;
    const int j    = j0 + w * 16 + n;           // this lane's owned h row
    const int b0   = grp * 16;

    // ---- register-resident weights (f32 -> bf16, once) ----
    short8 wfr[32];                              // wrec B-frags: B[k][j] = wrec[j][k]
#pragma unroll
    for (int kt = 0; kt < 32; ++kt)
        wfr[kt] = ld8f(&wrec[(size_t)j * H + kt * 32 + q * 8]);

    short8 wifr[4];                              // wi B-frags: B[k][j] = wi[k][j]
#pragma unroll
    for (int kt = 0; kt < 4; ++kt) {
        short8 v;
#pragma unroll
        for (int i = 0; i < 8; ++i)
            v[i] = (short)f2b(wi[(size_t)(kt * 32 + q * 8 + i) * H + j]);
        wifr[kt] = v;
    }
    short8 wofr[8];                              // wout B-frags, cols ji*8..+8, zero-pad n>=8
#pragma unroll
    for (int kk = 0; kk < 8; ++kk) {
        short8 v;
        const int kb = (w * 8 + kk) * 32 + q * 8;
#pragma unroll
        for (int i = 0; i < 8; ++i)
            v[i] = (n < 8) ? (short)f2b(wout[(size_t)(kb + i) * O_DIM + ji * 8 + n]) : (short)0;
        wofr[kk] = v;
    }

    const float gv = gg[j], bv = bb[j], h00 = h0p[j];
    float hreg[4];
#pragma unroll
    for (int r = 0; r < 4; ++r) hreg[r] = h00;

    const int kl    = w * 16 + n;                // local k in [0,64)
    const int off_l = (kl >> 5) * 512 + ((kl & 31) >> 3) * 128 + (kl & 7);
    const int slot  = ji * 4 + w;                // this wave's slice index

    // ---- publish-side chunk ids (lane -> 1 or 2 of the slice's 96 chunks) ----
    const int c1 = lane,      os1 = c1 / 3, p1 = c1 - os1 * 3;
    const int c2 = lane + 64, os2 = c2 / 3, p2 = c2 - os2 * 3;
    unsigned long long* const pub0 = aG + grp * GRP_U64 + slot * SLICE_U64;
    unsigned long long* const pub1 = pub0 + 4 * GRP_U64;
    const unsigned long long* const con0 = aG + grp * GRP_U64;
    const unsigned long long* const con1 = con0 + 4 * GRP_U64;

    // ---- consume-side chunk bases: wave w gathers k-tiles 8w..8w+7 (8 octets/lane)
    int coff[8];
#pragma unroll
    for (int i = 0; i < 8; ++i) {
        const int kt  = w * 8 + i;
        const int sub = lane >> 4;               // which k-octet inside the 32-k tile
        const int pw  = (kt & 1) * 2 + (sub >> 1);
        const int so  = sub & 1;
        const int m   = lane & 15;
        coff[i] = ((kt >> 1) * 4 + pw) * SLICE_U64 + (m * 2 + so) * 3;
    }

    // octet (m=os>>1, so=os&1) of own slice -> 48b data of chunk part p
    auto pack_chunk = [&](int os, int p) -> unsigned long long {
        const ull_alias* op = (const ull_alias*)&aloc[w * 256 + (os & 1) * 128 + (os >> 1) * 8];
        const unsigned long long lo = op[0], hi = op[1];
        unsigned long long d;
        if (p == 0)      d = lo & 0x0000FFFFFFFFFFFFull;                       // v0 v1 v2
        else if (p == 1) d = ((lo >> 48) | (hi << 16)) & 0x0000FFFFFFFFFFFFull; // v3 v4 v5
        else             d = ((hi >> 32) | ((hi >> 48) << 32)) & 0x0000FFFFFFFFFFFFull; // v6 v7 pad
        return d;
    };

    // fire-and-forget: pure relaxed stores, each chunk self-validating
    auto publish = [&](int t) {
        asm volatile("" ::: "memory");
        const unsigned long long tagv = (unsigned long long)(unsigned)t << 48;
        unsigned long long* dst = (t & 1) ? pub1 : pub0;
        __hip_atomic_store(&dst[c1], pack_chunk(os1, p1) | tagv,
                           __ATOMIC_RELAXED, __HIP_MEMORY_SCOPE_AGENT);
        if (lane < 32)
            __hip_atomic_store(&dst[c2], pack_chunk(os2, p2) | tagv,
                               __ATOMIC_RELAXED, __HIP_MEMORY_SCOPE_AGENT);
    };

    // poll-the-data: retry 24 chunk loads until every tag == tv, then unpack to abuf
    auto consume = [&](int tv) {
        const unsigned tt = (unsigned)tv;
        const unsigned long long* gb = (tv & 1) ? con1 : con0;
        unsigned long long v[24];
        for (;;) {
#pragma unroll
            for (int i = 0; i < 8; ++i) {
                const unsigned long long* cp = gb + coff[i];
                v[3*i  ] = __hip_atomic_load(cp,     __ATOMIC_RELAXED, __HIP_MEMORY_SCOPE_AGENT);
                v[3*i+1] = __hip_atomic_load(cp + 1, __ATOMIC_RELAXED, __HIP_MEMORY_SCOPE_AGENT);
                v[3*i+2] = __hip_atomic_load(cp + 2, __ATOMIC_RELAXED, __HIP_MEMORY_SCOPE_AGENT);
            }
            unsigned bad = 0;
#pragma unroll
            for (int c = 0; c < 24; ++c) bad |= (unsigned)(v[c] >> 48) ^ tt;
            if (__all(bad == 0)) break;
            __builtin_amdgcn_s_sleep(1);
        }
        asm volatile("" ::: "memory");
#pragma unroll
        for (int i = 0; i < 8; ++i) {
            const unsigned long long ca = v[3*i], cb = v[3*i+1], cc = v[3*i+2];
            const unsigned long long w01 = (ca & 0xFFFFFFFFull)
                | (((ca >> 32) & 0xFFFFull) << 32) | ((cb & 0xFFFFull) << 48);
            const unsigned long long w23 = ((cb >> 16) & 0xFFFFFFFFull) | (cc << 32);
            ull_alias* d = (ull_alias*)((char*)abuf + w * 8192 + (i * 64 + lane) * 16);
            d[0] = w01; d[1] = w23;
        }
    };

    // out[:, t, ji*8..+8) from abuf (full k=1024 chain)
    auto do_out = [&](int t) {
        f32x4 oa = {0.f, 0.f, 0.f, 0.f};
#pragma unroll
        for (int kk = 0; kk < 8; ++kk) {
            short8 af = *(const short8*)&abuf[(w * 8 + kk) * 512 + lane * 8];
            oa = __builtin_amdgcn_mfma_f32_16x16x32_bf16(af, wofr[kk], oa, 0, 0, 0);
        }
        if (n < 8) {
#pragma unroll
            for (int r = 0; r < 4; ++r) opart[w * 128 + (4 * q + r) * 8 + n] = oa[r];
        }
        __syncthreads();
        if (tid < 128) {
            float s = opart[tid] + opart[128 + tid] + opart[256 + tid] + opart[384 + tid];
            const int m = tid >> 3, c = tid & 7;
            out[((size_t)(b0 + m) * T_DIM + t) * O_DIM + ji * 8 + c] = s;
        }
    };

    // ---- init: stage + publish a0 = g*tanh(h0+b) (batch-broadcast) ----
    {
        unsigned short a0 = f2b(gv * tanh_fast(h00 + bv));
#pragma unroll
        for (int r = 0; r < 4; ++r) aloc[off_l + (4 * q + r) * 8] = a0;
        publish(0);
    }

    short8 xfr[4];                               // prefetch x[:,0,:]
#pragma unroll
    for (int kt = 0; kt < 4; ++kt)
        xfr[kt] = ld8f(&x[(size_t)(b0 + n) * T_DIM * I_DIM + kt * 32 + q * 8]);

    for (int t = 1; t < T_DIM; ++t) {
        // x@wi partials: register-only, overlaps stragglers
        f32x4 acc0 = {0.f,0.f,0.f,0.f}, acc1 = {0.f,0.f,0.f,0.f};
        acc0 = __builtin_amdgcn_mfma_f32_16x16x32_bf16(xfr[0], wifr[0], acc0, 0,0,0);
        acc1 = __builtin_amdgcn_mfma_f32_16x16x32_bf16(xfr[1], wifr[1], acc1, 0,0,0);
        acc0 = __builtin_amdgcn_mfma_f32_16x16x32_bf16(xfr[2], wifr[2], acc0, 0,0,0);
        acc1 = __builtin_amdgcn_mfma_f32_16x16x32_bf16(xfr[3], wifr[3], acc1, 0,0,0);

        __syncthreads();          // all waves done reading old abuf (do_out t-2)
        consume(t - 1);           // poll-the-data retry -> VGPR -> ds_write abuf
        __syncthreads();          // abuf complete & visible to all waves

        // + a_{t-1} @ wrec^T
#pragma unroll
        for (int kt = 0; kt < 32; kt += 2) {
            short8 a0f = *(const short8*)&abuf[kt * 512 + lane * 8];
            short8 a1f = *(const short8*)&abuf[(kt + 1) * 512 + lane * 8];
            acc0 = __builtin_amdgcn_mfma_f32_16x16x32_bf16(a0f, wfr[kt],     acc0, 0,0,0);
            acc1 = __builtin_amdgcn_mfma_f32_16x16x32_bf16(a1f, wfr[kt + 1], acc1, 0,0,0);
        }

        // h update; stage a_t in aloc (wave-private region), publish immediately
#pragma unroll
        for (int r = 0; r < 4; ++r) {
            float z  = acc0[r] + acc1[r];
            float hv = (1.0f - ALPHA) * hreg[r] + ALPHA * z;
            hreg[r] = hv;
            aloc[off_l + (4 * q + r) * 8] = f2b(gv * tanh_fast(hv + bv));
        }
        publish(t);

        // off critical path: x prefetch + out for step t-1
        if (t < T_DIM - 1) {
#pragma unroll
            for (int kt = 0; kt < 4; ++kt)
                xfr[kt] = ld8f(&x[((size_t)(b0 + n) * T_DIM + t) * I_DIM + kt * 32 + q * 8]);
        }
        do_out(t - 1);
    }

    // epilogue: out[:, 511, :] from a_511
    __syncthreads();
    consume(T_DIM - 1);
    __syncthreads();
    do_out(T_DIM - 1);
}

extern "C" void kernel_launch(void* const* d_in, const int* in_sizes, int n_in,
                              void* d_out, int out_size, void* d_ws, size_t ws_size,
                              hipStream_t stream) {
    const float* x    = (const float*)d_in[0];
    const float* wi   = (const float*)d_in[1];
    const float* wrec = (const float*)d_in[2];
    const float* wout = (const float*)d_in[3];
    const float* bb   = (const float*)d_in[4];
    const float* gg   = (const float*)d_in[5];
    const float* h0   = (const float*)d_in[6];
    float* outp = (float*)d_out;

    unsigned long long* aG = (unsigned long long*)d_ws;   // 2 x 4 x 48 KB = 384 KB

    // reset all chunk tags to 0xFFFF (never matches any t < 512) so a graph
    // replay can't confuse the previous run's chunks with this run's
    hipMemsetAsync(d_ws, 0xFF, (size_t)2 * 4 * GRP_U64 * 8, stream);
    hipLaunchKernelGGL(rnn_kernel, dim3(NWG), dim3(256), 0, stream,
                       x, wi, wrec, wout, bb, gg, h0, outp, aG);
}

// Round 2
// 1846.964 us; speedup vs baseline: 1.1486x; 1.1486x over previous
//
#include <hip/hip_runtime.h>

#define H 1024
#define I_DIM 128
#define O_DIM 128
#define T_DIM 512
#define ALPHA 0.2f
#define NWG 64            // 4 batch-groups x 16 j-slices
#define GSZ 16            // WGs per batch-group
#define PLANE_U64 2048    // 64 slices x 32 octets, one u64 chunk each
#define GRP_U64   (3 * PLANE_U64)   // 6144 u64 = 48 KB per (parity, group)

typedef short short8 __attribute__((ext_vector_type(8)));
typedef float f32x4 __attribute__((ext_vector_type(4)));
typedef unsigned long long ull_alias __attribute__((may_alias));

__device__ __forceinline__ unsigned short f2b(float f) {
    union { float f; unsigned u; } x; x.f = f;
    unsigned u = x.u;
    return (unsigned short)((u + 0x7FFFu + ((u >> 16) & 1u)) >> 16);
}
__device__ __forceinline__ float tanh_fast(float x) {
    float e = __expf(2.0f * x);
    return 1.0f - 2.0f * __builtin_amdgcn_rcpf(e + 1.0f);
}
// 8 contiguous f32 -> bf16 fragment (RNE)
__device__ __forceinline__ short8 ld8f(const float* __restrict__ p) {
    const float4 a = *(const float4*)p;
    const float4 b = *(const float4*)(p + 4);
    short8 r;
    r[0]=(short)f2b(a.x); r[1]=(short)f2b(a.y); r[2]=(short)f2b(a.z); r[3]=(short)f2b(a.w);
    r[4]=(short)f2b(b.x); r[5]=(short)f2b(b.y); r[6]=(short)f2b(b.z); r[7]=(short)f2b(b.w);
    return r;
}
__device__ __forceinline__ short8 pack8(float4 a, float4 b) {
    short8 r;
    r[0]=(short)f2b(a.x); r[1]=(short)f2b(a.y); r[2]=(short)f2b(a.z); r[3]=(short)f2b(a.w);
    r[4]=(short)f2b(b.x); r[5]=(short)f2b(b.y); r[6]=(short)f2b(b.z); r[7]=(short)f2b(b.w);
    return r;
}

// Packed-A layout per batch-group: A[m][k] at u16 offset
//   (k>>5)*512 + ((k&31)>>3)*128 + m*8 + (k&7)
// Cross-WG exchange: slice s = ji*4+w publishes 32 octets (16 m x 2 k-suboctets,
// octet o = m*2+so). Each octet is split into 3 self-validating 8B chunks
// (48b data + 16b step tag), stored plane-wise: chunk(s,o,p) at
// plane_p[s*32+o]. Producer stores and consumer poll-loads are BOTH
// lane-contiguous (this is the fix for R1's 48B-stride scatter).
// Publish is fire-and-forget (no vmcnt, no tag store); the consumer's
// successful poll IS the fetch. Stale tags killed by 0xFF memset per launch.
__global__ __launch_bounds__(256, 1) void rnn_kernel(
    const float* __restrict__ x, const float* __restrict__ wi,
    const float* __restrict__ wrec, const float* __restrict__ wout,
    const float* __restrict__ bb, const float* __restrict__ gg,
    const float* __restrict__ h0p, float* __restrict__ out,
    unsigned long long* __restrict__ aG)
{
    __shared__ unsigned short abuf[32 * 512];   // 32 KB: group's full a_{t-1}
    __shared__ unsigned short aloc[1024];       // 2 KB: own a_t slice, packed
    __shared__ float opart[4 * 128];            // 2 KB: out k-partials

    const int tid  = threadIdx.x;
    const int w    = tid >> 6, lane = tid & 63;
    const int n    = lane & 15, q = lane >> 4;
    const int grp  = blockIdx.x & 3;
    const int ji   = blockIdx.x >> 2;
    const int j0   = ji * 64;
    const int j    = j0 + w * 16 + n;           // this lane's owned h row
    const int b0   = grp * 16;

    // ---- register-resident weights (f32 -> bf16, once) ----
    short8 wfr[32];                              // wrec B-frags: B[k][j] = wrec[j][k]
#pragma unroll
    for (int kt = 0; kt < 32; ++kt)
        wfr[kt] = ld8f(&wrec[(size_t)j * H + kt * 32 + q * 8]);

    short8 wifr[4];                              // wi B-frags: B[k][j] = wi[k][j]
#pragma unroll
    for (int kt = 0; kt < 4; ++kt) {
        short8 v;
#pragma unroll
        for (int i = 0; i < 8; ++i)
            v[i] = (short)f2b(wi[(size_t)(kt * 32 + q * 8 + i) * H + j]);
        wifr[kt] = v;
    }
    short8 wofr[8];                              // wout B-frags, cols ji*8..+8, zero-pad n>=8
#pragma unroll
    for (int kk = 0; kk < 8; ++kk) {
        short8 v;
        const int kb = (w * 8 + kk) * 32 + q * 8;
#pragma unroll
        for (int i = 0; i < 8; ++i)
            v[i] = (n < 8) ? (short)f2b(wout[(size_t)(kb + i) * O_DIM + ji * 8 + n]) : (short)0;
        wofr[kk] = v;
    }

    const float gv = gg[j], bv = bb[j], h00 = h0p[j];
    float hreg[4];
#pragma unroll
    for (int r = 0; r < 4; ++r) hreg[r] = h00;

    const int kl    = w * 16 + n;                // local k in [0,64)
    const int off_l = (kl >> 5) * 512 + ((kl & 31) >> 3) * 128 + (kl & 7);
    const int s_sl  = ji * 4 + w;                // this wave's slice index

    unsigned long long* const gB0 = aG + grp * GRP_U64;            // parity 0
    unsigned long long* const gB1 = aG + (4 + grp) * GRP_U64;      // parity 1

    // publish chunk slots (lane-contiguous per half-wave / 32-lane group)
    const int pubA = (lane >> 5) * PLANE_U64 + s_sl * 32 + (lane & 31);  // parts 0/1
    const int pubB = 2 * PLANE_U64 + s_sl * 32 + lane;                    // part 2, lane<32
    const int oA   = lane & 31;

    // consume base: wave w owns octet-index range [512w, 512w+512) in each plane
    const int cbase = w * 512 + lane;

    // unpack destinations (byte offsets into abuf), one per load index i
    int doff[8];
#pragma unroll
    for (int i = 0; i < 8; ++i) {
        const int idx = i * 64 + lane;
        const int s   = 16 * w + (idx >> 5);     // producing slice
        const int oo  = idx & 31;                // octet within slice
        const int m   = oo >> 1, so = oo & 1;
        const int k0  = (s >> 2) * 64 + (s & 3) * 16 + so * 8;
        doff[i] = ((k0 >> 5) * 512 + ((k0 & 31) >> 3) * 128 + m * 8) * 2;
    }

    // fire-and-forget: coalesced relaxed agent stores, chunks self-validating
    auto publish = [&](int t) {
        asm volatile("" ::: "memory");
        const unsigned long long tagv = (unsigned long long)(unsigned)t << 48;
        unsigned long long* gb = (t & 1) ? gB1 : gB0;
        {
            const ull_alias* opq = (const ull_alias*)&aloc[w * 256 + (oA & 1) * 128 + (oA >> 1) * 8];
            const unsigned long long lo = opq[0], hi = opq[1];
            const unsigned long long d0 = lo & 0x0000FFFFFFFFFFFFull;                        // v0 v1 v2
            const unsigned long long d1 = ((lo >> 48) | (hi << 16)) & 0x0000FFFFFFFFFFFFull; // v3 v4 v5
            __hip_atomic_store(gb + pubA, ((lane < 32) ? d0 : d1) | tagv,
                               __ATOMIC_RELAXED, __HIP_MEMORY_SCOPE_AGENT);
        }
        if (lane < 32) {
            const ull_alias* opq = (const ull_alias*)&aloc[w * 256 + (lane & 1) * 128 + (lane >> 1) * 8];
            const unsigned long long hi = opq[1];
            const unsigned long long d2 = ((hi >> 32) & 0xFFFFFFFFull) | tagv;               // v6 v7
            __hip_atomic_store(gb + pubB, d2, __ATOMIC_RELAXED, __HIP_MEMORY_SCOPE_AGENT);
        }
    };

    // poll-the-data: 24 lane-contiguous loads, retry until every tag == tv,
    // then recombine triples -> abuf (the poll IS the fetch)
    auto consume = [&](int tv) {
        const unsigned tt = (unsigned)tv;
        const unsigned long long* gb = (tv & 1) ? gB1 : gB0;
        unsigned long long v0[8], v1[8], v2[8];
        for (;;) {
#pragma unroll
            for (int i = 0; i < 8; ++i) {
                v0[i] = __hip_atomic_load(gb + cbase + i * 64,
                                          __ATOMIC_RELAXED, __HIP_MEMORY_SCOPE_AGENT);
                v1[i] = __hip_atomic_load(gb + PLANE_U64 + cbase + i * 64,
                                          __ATOMIC_RELAXED, __HIP_MEMORY_SCOPE_AGENT);
                v2[i] = __hip_atomic_load(gb + 2 * PLANE_U64 + cbase + i * 64,
                                          __ATOMIC_RELAXED, __HIP_MEMORY_SCOPE_AGENT);
            }
            unsigned bad = 0;
#pragma unroll
            for (int i = 0; i < 8; ++i)
                bad |= ((unsigned)(v0[i] >> 48) ^ tt) | ((unsigned)(v1[i] >> 48) ^ tt)
                     | ((unsigned)(v2[i] >> 48) ^ tt);
            if (__all(bad == 0)) break;
            __builtin_amdgcn_s_sleep(1);
        }
        asm volatile("" ::: "memory");
#pragma unroll
        for (int i = 0; i < 8; ++i) {
            const unsigned long long ca = v0[i], cb = v1[i], cc = v2[i];
            const unsigned long long w01 = (ca & 0xFFFFFFFFull)
                | (((ca >> 32) & 0xFFFFull) << 32) | ((cb & 0xFFFFull) << 48);   // v0..v3
            const unsigned long long w23 = ((cb >> 16) & 0xFFFFFFFFull) | (cc << 32); // v4..v7
            ull_alias* d = (ull_alias*)((char*)abuf + doff[i]);
            d[0] = w01; d[1] = w23;
        }
    };

    // out[:, t, ji*8..+8) from abuf (full k=1024 chain)
    auto do_out = [&](int t) {
        f32x4 oa = {0.f, 0.f, 0.f, 0.f};
#pragma unroll
        for (int kk = 0; kk < 8; ++kk) {
            short8 af = *(const short8*)&abuf[(w * 8 + kk) * 512 + lane * 8];
            oa = __builtin_amdgcn_mfma_f32_16x16x32_bf16(af, wofr[kk], oa, 0, 0, 0);
        }
        if (n < 8) {
#pragma unroll
            for (int r = 0; r < 4; ++r) opart[w * 128 + (4 * q + r) * 8 + n] = oa[r];
        }
        __syncthreads();
        if (tid < 128) {
            float s = opart[tid] + opart[128 + tid] + opart[256 + tid] + opart[384 + tid];
            const int m = tid >> 3, c = tid & 7;
            out[((size_t)(b0 + m) * T_DIM + t) * O_DIM + ji * 8 + c] = s;
        }
    };

    // ---- init: stage + publish a0 = g*tanh(h0+b) (batch-broadcast) ----
    {
        unsigned short a0 = f2b(gv * tanh_fast(h00 + bv));
#pragma unroll
        for (int r = 0; r < 4; ++r) aloc[off_l + (4 * q + r) * 8] = a0;
        publish(0);
    }

    short8 xfr[4];                               // packed x[:,0,:]
#pragma unroll
    for (int kt = 0; kt < 4; ++kt)
        xfr[kt] = ld8f(&x[(size_t)(b0 + n) * T_DIM * I_DIM + kt * 32 + q * 8]);

    float4 xr[8];                                // raw f32 prefetch (issue-early/pack-late)

    for (int t = 1; t < T_DIM; ++t) {
        // issue next-step x loads immediately: latency hides under consume+MFMA
        if (t < T_DIM - 1) {
            const float* xp = &x[((size_t)(b0 + n) * T_DIM + t) * I_DIM];
#pragma unroll
            for (int kt = 0; kt < 4; ++kt) {
                xr[2 * kt]     = *(const float4*)(xp + kt * 32 + q * 8);
                xr[2 * kt + 1] = *(const float4*)(xp + kt * 32 + q * 8 + 4);
            }
        }

        // x@wi partials: register-only, overlaps stragglers
        f32x4 acc0 = {0.f,0.f,0.f,0.f}, acc1 = {0.f,0.f,0.f,0.f};
        acc0 = __builtin_amdgcn_mfma_f32_16x16x32_bf16(xfr[0], wifr[0], acc0, 0,0,0);
        acc1 = __builtin_amdgcn_mfma_f32_16x16x32_bf16(xfr[1], wifr[1], acc1, 0,0,0);
        acc0 = __builtin_amdgcn_mfma_f32_16x16x32_bf16(xfr[2], wifr[2], acc0, 0,0,0);
        acc1 = __builtin_amdgcn_mfma_f32_16x16x32_bf16(xfr[3], wifr[3], acc1, 0,0,0);

        __syncthreads();          // all waves done reading old abuf (do_out t-2)
        consume(t - 1);           // fused detect+fetch -> VGPR -> ds_write abuf
        __syncthreads();          // abuf complete & visible to all waves

        // + a_{t-1} @ wrec^T
#pragma unroll
        for (int kt = 0; kt < 32; kt += 2) {
            short8 a0f = *(const short8*)&abuf[kt * 512 + lane * 8];
            short8 a1f = *(const short8*)&abuf[(kt + 1) * 512 + lane * 8];
            acc0 = __builtin_amdgcn_mfma_f32_16x16x32_bf16(a0f, wfr[kt],     acc0, 0,0,0);
            acc1 = __builtin_amdgcn_mfma_f32_16x16x32_bf16(a1f, wfr[kt + 1], acc1, 0,0,0);
        }

        // h update; stage a_t in aloc (wave-private region), publish immediately
#pragma unroll
        for (int r = 0; r < 4; ++r) {
            float z  = acc0[r] + acc1[r];
            float hv = (1.0f - ALPHA) * hreg[r] + ALPHA * z;
            hreg[r] = hv;
            aloc[off_l + (4 * q + r) * 8] = f2b(gv * tanh_fast(hv + bv));
        }
        publish(t);

        // off critical path: pack the already-loaded x + out for step t-1
        if (t < T_DIM - 1) {
#pragma unroll
            for (int kt = 0; kt < 4; ++kt)
                xfr[kt] = pack8(xr[2 * kt], xr[2 * kt + 1]);
        }
        do_out(t - 1);
    }

    // epilogue: out[:, 511, :] from a_511
    __syncthreads();
    consume(T_DIM - 1);
    __syncthreads();
    do_out(T_DIM - 1);
}

extern "C" void kernel_launch(void* const* d_in, const int* in_sizes, int n_in,
                              void* d_out, int out_size, void* d_ws, size_t ws_size,
                              hipStream_t stream) {
    const float* x    = (const float*)d_in[0];
    const float* wi   = (const float*)d_in[1];
    const float* wrec = (const float*)d_in[2];
    const float* wout = (const float*)d_in[3];
    const float* bb   = (const float*)d_in[4];
    const float* gg   = (const float*)d_in[5];
    const float* h0   = (const float*)d_in[6];
    float* outp = (float*)d_out;

    unsigned long long* aG = (unsigned long long*)d_ws;   // 2 x 4 x 48 KB = 384 KB

    // reset all chunk tags to 0xFFFF (never matches any t < 512) so a graph
    // replay can't confuse the previous run's chunks with this run's
    hipMemsetAsync(d_ws, 0xFF, (size_t)2 * 4 * GRP_U64 * 8, stream);
    hipLaunchKernelGGL(rnn_kernel, dim3(NWG), dim3(256), 0, stream,
                       x, wi, wrec, wout, bb, gg, h0, outp, aG);
}

// Round 3
// 1789.121 us; speedup vs baseline: 1.1858x; 1.0323x over previous
//
#include <hip/hip_runtime.h>

#define H 1024
#define I_DIM 128
#define O_DIM 128
#define T_DIM 512
#define ALPHA 0.2f
#define NWG 64            // 4 batch-groups x 16 j-slices
#define GSZ 16            // WGs per batch-group
#define PLANE_U64 2048    // 64 slices x 32 octets, one u64 chunk each
#define GRP_U64   (3 * PLANE_U64)   // 6144 u64 = 48 KB per (parity, group)

typedef short short8 __attribute__((ext_vector_type(8)));
typedef float f32x4 __attribute__((ext_vector_type(4)));
typedef unsigned long long ull_alias __attribute__((may_alias));

__device__ __forceinline__ unsigned short f2b(float f) {
    union { float f; unsigned u; } x; x.f = f;
    unsigned u = x.u;
    return (unsigned short)((u + 0x7FFFu + ((u >> 16) & 1u)) >> 16);
}
__device__ __forceinline__ float tanh_fast(float x) {
    float e = __expf(2.0f * x);
    return 1.0f - 2.0f * __builtin_amdgcn_rcpf(e + 1.0f);
}
// 8 contiguous f32 -> bf16 fragment (RNE)
__device__ __forceinline__ short8 ld8f(const float* __restrict__ p) {
    const float4 a = *(const float4*)p;
    const float4 b = *(const float4*)(p + 4);
    short8 r;
    r[0]=(short)f2b(a.x); r[1]=(short)f2b(a.y); r[2]=(short)f2b(a.z); r[3]=(short)f2b(a.w);
    r[4]=(short)f2b(b.x); r[5]=(short)f2b(b.y); r[6]=(short)f2b(b.z); r[7]=(short)f2b(b.w);
    return r;
}
__device__ __forceinline__ short8 pack8(float4 a, float4 b) {
    short8 r;
    r[0]=(short)f2b(a.x); r[1]=(short)f2b(a.y); r[2]=(short)f2b(a.z); r[3]=(short)f2b(a.w);
    r[4]=(short)f2b(b.x); r[5]=(short)f2b(b.y); r[6]=(short)f2b(b.z); r[7]=(short)f2b(b.w);
    return r;
}

// Packed-A layout per batch-group: A[m][k] at u16 offset
//   (k>>5)*512 + ((k&31)>>3)*128 + m*8 + (k&7)
// Cross-WG exchange: slice s = ji*4+w publishes 32 octets (o = m*2+so), each as
// THREE self-validating 8B chunks (48b data + 16b tag) at plane_p[s*32+o].
// R3 changes:
//  (A) consume split into issue-early (loop top, overlaps do_out/x/barrier)
//      + check-late (after sync#1). Retry path == old behavior, so >= as good.
//  (B) consume lane->octet remap: unpack dest is LINEAR (contiguous b128,
//      conflict-minimal), load offset perm(lane) keeps 512B/instr coalescing.
__global__ __launch_bounds__(256, 1) void rnn_kernel(
    const float* __restrict__ x, const float* __restrict__ wi,
    const float* __restrict__ wrec, const float* __restrict__ wout,
    const float* __restrict__ bb, const float* __restrict__ gg,
    const float* __restrict__ h0p, float* __restrict__ out,
    unsigned long long* __restrict__ aG)
{
    __shared__ unsigned short abuf[32 * 512];   // 32 KB: group's full a_{t-1}
    __shared__ unsigned short aloc[1024];       // 2 KB: own a_t slice, packed
    __shared__ float opart[4 * 128];            // 2 KB: out k-partials

    const int tid  = threadIdx.x;
    const int w    = tid >> 6, lane = tid & 63;
    const int n    = lane & 15, q = lane >> 4;
    const int grp  = blockIdx.x & 3;
    const int ji   = blockIdx.x >> 2;
    const int j0   = ji * 64;
    const int j    = j0 + w * 16 + n;           // this lane's owned h row
    const int b0   = grp * 16;

    // ---- register-resident weights (f32 -> bf16, once) ----
    short8 wfr[32];                              // wrec B-frags: B[k][j] = wrec[j][k]
#pragma unroll
    for (int kt = 0; kt < 32; ++kt)
        wfr[kt] = ld8f(&wrec[(size_t)j * H + kt * 32 + q * 8]);

    short8 wifr[4];                              // wi B-frags: B[k][j] = wi[k][j]
#pragma unroll
    for (int kt = 0; kt < 4; ++kt) {
        short8 v;
#pragma unroll
        for (int i = 0; i < 8; ++i)
            v[i] = (short)f2b(wi[(size_t)(kt * 32 + q * 8 + i) * H + j]);
        wifr[kt] = v;
    }
    short8 wofr[8];                              // wout B-frags, cols ji*8..+8, zero-pad n>=8
#pragma unroll
    for (int kk = 0; kk < 8; ++kk) {
        short8 v;
        const int kb = (w * 8 + kk) * 32 + q * 8;
#pragma unroll
        for (int i = 0; i < 8; ++i)
            v[i] = (n < 8) ? (short)f2b(wout[(size_t)(kb + i) * O_DIM + ji * 8 + n]) : (short)0;
        wofr[kk] = v;
    }

    const float gv = gg[j], bv = bb[j], h00 = h0p[j];
    float hreg[4];
#pragma unroll
    for (int r = 0; r < 4; ++r) hreg[r] = h00;

    const int kl    = w * 16 + n;                // local k in [0,64)
    const int off_l = (kl >> 5) * 512 + ((kl & 31) >> 3) * 128 + (kl & 7);
    const int s_sl  = ji * 4 + w;                // this wave's slice index

    unsigned long long* const gB0 = aG + grp * GRP_U64;            // parity 0
    unsigned long long* const gB1 = aG + (4 + grp) * GRP_U64;      // parity 1

    // publish chunk slots (lane-contiguous per half-wave / 32-lane group)
    const int pubA = (lane >> 5) * PLANE_U64 + s_sl * 32 + (lane & 31);  // parts 0/1
    const int pubB = 2 * PLANE_U64 + s_sl * 32 + lane;                    // part 2, lane<32
    const int oA   = lane & 31;

    // consume: remapped lane->octet so the unpack dest is linear.
    //   load u64 offset  = w*512 + perm(lane) + i*64  (contiguous 512B/instr)
    //   unpack dest byte = w*8192 + (i*64+lane)*16    (contiguous b128 writes)
    const int perm  = (lane >> 5) * 32 + (lane & 15) * 2 + ((lane >> 4) & 1);
    const int cb    = w * 512 + perm;

    // fire-and-forget: coalesced relaxed agent stores, chunks self-validating
    auto publish = [&](int t) {
        asm volatile("" ::: "memory");
        const unsigned long long tagv = (unsigned long long)(unsigned)t << 48;
        unsigned long long* gb = (t & 1) ? gB1 : gB0;
        {
            const ull_alias* opq = (const ull_alias*)&aloc[w * 256 + (oA & 1) * 128 + (oA >> 1) * 8];
            const unsigned long long lo = opq[0], hi = opq[1];
            const unsigned long long d0 = lo & 0x0000FFFFFFFFFFFFull;                        // v0 v1 v2
            const unsigned long long d1 = ((lo >> 48) | (hi << 16)) & 0x0000FFFFFFFFFFFFull; // v3 v4 v5
            __hip_atomic_store(gb + pubA, ((lane < 32) ? d0 : d1) | tagv,
                               __ATOMIC_RELAXED, __HIP_MEMORY_SCOPE_AGENT);
        }
        if (lane < 32) {
            const ull_alias* opq = (const ull_alias*)&aloc[w * 256 + (lane & 1) * 128 + (lane >> 1) * 8];
            const unsigned long long hi = opq[1];
            const unsigned long long d2 = ((hi >> 32) & 0xFFFFFFFFull) | tagv;               // v6 v7
            __hip_atomic_store(gb + pubB, d2, __ATOMIC_RELAXED, __HIP_MEMORY_SCOPE_AGENT);
        }
    };

    // speculative sample: 24 lane-contiguous loads into registers
    auto poll_issue = [&](const unsigned long long* gb,
                          unsigned long long* v0, unsigned long long* v1,
                          unsigned long long* v2) {
#pragma unroll
        for (int i = 0; i < 8; ++i) {
            v0[i] = __hip_atomic_load(gb + cb + i * 64,
                                      __ATOMIC_RELAXED, __HIP_MEMORY_SCOPE_AGENT);
            v1[i] = __hip_atomic_load(gb + PLANE_U64 + cb + i * 64,
                                      __ATOMIC_RELAXED, __HIP_MEMORY_SCOPE_AGENT);
            v2[i] = __hip_atomic_load(gb + 2 * PLANE_U64 + cb + i * 64,
                                      __ATOMIC_RELAXED, __HIP_MEMORY_SCOPE_AGENT);
        }
    };

    // late check: if any tag stale, fall back to the old retry loop
    auto poll_check = [&](int tv, const unsigned long long* gb,
                          unsigned long long* v0, unsigned long long* v1,
                          unsigned long long* v2) {
        const unsigned tt = (unsigned)tv;
        for (;;) {
            unsigned bad = 0;
#pragma unroll
            for (int i = 0; i < 8; ++i)
                bad |= ((unsigned)(v0[i] >> 48) ^ tt) | ((unsigned)(v1[i] >> 48) ^ tt)
                     | ((unsigned)(v2[i] >> 48) ^ tt);
            if (__all(bad == 0)) break;
            __builtin_amdgcn_s_sleep(1);
            poll_issue(gb, v0, v1, v2);
        }
        asm volatile("" ::: "memory");
    };

    // recombine triples -> abuf, linear contiguous b128 writes
    auto unpack = [&](const unsigned long long* v0, const unsigned long long* v1,
                      const unsigned long long* v2) {
#pragma unroll
        for (int i = 0; i < 8; ++i) {
            const unsigned long long ca = v0[i], cb_ = v1[i], cc = v2[i];
            const unsigned long long w01 = (ca & 0xFFFFFFFFull)
                | (((ca >> 32) & 0xFFFFull) << 32) | ((cb_ & 0xFFFFull) << 48);   // v0..v3
            const unsigned long long w23 = ((cb_ >> 16) & 0xFFFFFFFFull) | (cc << 32); // v4..v7
            ull_alias* d = (ull_alias*)((char*)abuf + w * 8192 + (i * 64 + lane) * 16);
            d[0] = w01; d[1] = w23;
        }
    };

    // out[:, t, ji*8..+8) from abuf (full k=1024 chain)
    auto do_out = [&](int t) {
        f32x4 oa = {0.f, 0.f, 0.f, 0.f};
#pragma unroll
        for (int kk = 0; kk < 8; ++kk) {
            short8 af = *(const short8*)&abuf[(w * 8 + kk) * 512 + lane * 8];
            oa = __builtin_amdgcn_mfma_f32_16x16x32_bf16(af, wofr[kk], oa, 0, 0, 0);
        }
        if (n < 8) {
#pragma unroll
            for (int r = 0; r < 4; ++r) opart[w * 128 + (4 * q + r) * 8 + n] = oa[r];
        }
        __syncthreads();
        if (tid < 128) {
            float s = opart[tid] + opart[128 + tid] + opart[256 + tid] + opart[384 + tid];
            const int m = tid >> 3, c = tid & 7;
            out[((size_t)(b0 + m) * T_DIM + t) * O_DIM + ji * 8 + c] = s;
        }
    };

    // ---- init: stage + publish a0 = g*tanh(h0+b) (batch-broadcast) ----
    {
        unsigned short a0 = f2b(gv * tanh_fast(h00 + bv));
#pragma unroll
        for (int r = 0; r < 4; ++r) aloc[off_l + (4 * q + r) * 8] = a0;
        publish(0);
    }

    short8 xfr[4];                               // packed x[:,0,:]
#pragma unroll
    for (int kt = 0; kt < 4; ++kt)
        xfr[kt] = ld8f(&x[(size_t)(b0 + n) * T_DIM * I_DIM + kt * 32 + q * 8]);

    float4 xr[8];                                // raw f32 prefetch (issue-early/pack-late)
    unsigned long long pv0[8], pv1[8], pv2[8];   // speculative poll values

    for (int t = 1; t < T_DIM; ++t) {
        const unsigned long long* gb = ((t - 1) & 1) ? gB1 : gB0;

        // (A) speculative poll-issue FIRST: samples while peers' stores land;
        //     result checked only after sync#1, hiding the LLC round trip.
        poll_issue(gb, pv0, pv1, pv2);

        // next-step x loads: issued after polls so the check can drain polls first
        if (t < T_DIM - 1) {
            const float* xp = &x[((size_t)(b0 + n) * T_DIM + t) * I_DIM];
#pragma unroll
            for (int kt = 0; kt < 4; ++kt) {
                xr[2 * kt]     = *(const float4*)(xp + kt * 32 + q * 8);
                xr[2 * kt + 1] = *(const float4*)(xp + kt * 32 + q * 8 + 4);
            }
        }

        // x@wi partials: register-only, overlaps the in-flight loads
        f32x4 acc0 = {0.f,0.f,0.f,0.f}, acc1 = {0.f,0.f,0.f,0.f};
        acc0 = __builtin_amdgcn_mfma_f32_16x16x32_bf16(xfr[0], wifr[0], acc0, 0,0,0);
        acc1 = __builtin_amdgcn_mfma_f32_16x16x32_bf16(xfr[1], wifr[1], acc1, 0,0,0);
        acc0 = __builtin_amdgcn_mfma_f32_16x16x32_bf16(xfr[2], wifr[2], acc0, 0,0,0);
        acc1 = __builtin_amdgcn_mfma_f32_16x16x32_bf16(xfr[3], wifr[3], acc1, 0,0,0);

        __syncthreads();          // all waves done reading old abuf (do_out t-2)
        poll_check(t - 1, gb, pv0, pv1, pv2);   // usually already satisfied
        unpack(pv0, pv1, pv2);                  // (B) linear conflict-minimal ds_writes
        __syncthreads();          // abuf complete & visible to all waves

        // + a_{t-1} @ wrec^T
#pragma unroll
        for (int kt = 0; kt < 32; kt += 2) {
            short8 a0f = *(const short8*)&abuf[kt * 512 + lane * 8];
            short8 a1f = *(const short8*)&abuf[(kt + 1) * 512 + lane * 8];
            acc0 = __builtin_amdgcn_mfma_f32_16x16x32_bf16(a0f, wfr[kt],     acc0, 0,0,0);
            acc1 = __builtin_amdgcn_mfma_f32_16x16x32_bf16(a1f, wfr[kt + 1], acc1, 0,0,0);
        }

        // h update; stage a_t in aloc (wave-private region), publish immediately
#pragma unroll
        for (int r = 0; r < 4; ++r) {
            float z  = acc0[r] + acc1[r];
            float hv = (1.0f - ALPHA) * hreg[r] + ALPHA * z;
            hreg[r] = hv;
            aloc[off_l + (4 * q + r) * 8] = f2b(gv * tanh_fast(hv + bv));
        }
        publish(t);

        // off critical path: pack the already-loaded x + out for step t-1
        if (t < T_DIM - 1) {
#pragma unroll
            for (int kt = 0; kt < 4; ++kt)
                xfr[kt] = pack8(xr[2 * kt], xr[2 * kt + 1]);
        }
        do_out(t - 1);
    }

    // epilogue: out[:, 511, :] from a_511
    {
        const unsigned long long* gb = ((T_DIM - 1) & 1) ? gB1 : gB0;
        poll_issue(gb, pv0, pv1, pv2);
        __syncthreads();
        poll_check(T_DIM - 1, gb, pv0, pv1, pv2);
        unpack(pv0, pv1, pv2);
        __syncthreads();
        do_out(T_DIM - 1);
    }
}

extern "C" void kernel_launch(void* const* d_in, const int* in_sizes, int n_in,
                              void* d_out, int out_size, void* d_ws, size_t ws_size,
                              hipStream_t stream) {
    const float* x    = (const float*)d_in[0];
    const float* wi   = (const float*)d_in[1];
    const float* wrec = (const float*)d_in[2];
    const float* wout = (const float*)d_in[3];
    const float* bb   = (const float*)d_in[4];
    const float* gg   = (const float*)d_in[5];
    const float* h0   = (const float*)d_in[6];
    float* outp = (float*)d_out;

    unsigned long long* aG = (unsigned long long*)d_ws;   // 2 x 4 x 48 KB = 384 KB

    // reset all chunk tags to 0xFFFF (never matches any t < 512) so a graph
    // replay can't confuse the previous run's chunks with this run's
    hipMemsetAsync(d_ws, 0xFF, (size_t)2 * 4 * GRP_U64 * 8, stream);
    hipLaunchKernelGGL(rnn_kernel, dim3(NWG), dim3(256), 0, stream,
                       x, wi, wrec, wout, bb, gg, h0, outp, aG);
}